// Round 3
// baseline (249.756 us; speedup 1.0000x reference)
//
#include <hip/hip_runtime.h>

// OPT attention: B=16 T=4 E=2048 H=32 HD=64 P=4096 S=4100, M=B*T=64 rows.
// 4-dispatch design: k_qkvp (full-K per wave-tile, no partials) -> k_flash
// (register scores, LDS-staged bf16 V) -> k_merge -> k_out (in-block K-split).
// MFMA mfma_f32_16x16x32_bf16: A[m=lane&15][k=quad*8+j], B[n=lane&15][k=quad*8+j],
// D col=lane&15, row=quad*4+reg (verified layouts). Output dtype: f32.

typedef float f4 __attribute__((ext_vector_type(4)));
typedef short s8v __attribute__((ext_vector_type(8)));

#define NEG_HUGE (-3.402823466e38f)

__device__ inline unsigned short f2bs(float x) {  // f32 -> bf16 bits (RNE)
  union { float f; unsigned int u; } a; a.f = x;
  unsigned int u = a.u;
  u += 0x7fffu + ((u >> 16) & 1u);
  return (unsigned short)(u >> 16);
}
__device__ inline float bs2f(unsigned short s) {
  union { unsigned int u; float f; } a; a.u = ((unsigned int)s) << 16;
  return a.f;
}
__device__ inline s8v cvt8(f4 a, f4 b) {
  s8v r;
  r[0]=(short)f2bs(a[0]); r[1]=(short)f2bs(a[1]); r[2]=(short)f2bs(a[2]); r[3]=(short)f2bs(a[3]);
  r[4]=(short)f2bs(b[0]); r[5]=(short)f2bs(b[1]); r[6]=(short)f2bs(b[2]); r[7]=(short)f2bs(b[3]);
  return r;
}
__device__ inline f4 mfma16(s8v a, s8v b, f4 c) {
  return __builtin_amdgcn_mfma_f32_16x16x32_bf16(a, b, c, 0, 0, 0);
}
__device__ inline f4 fzero() { f4 z = {0.f,0.f,0.f,0.f}; return z; }
__device__ inline float wave_sum(float v) {
  #pragma unroll
  for (int off = 32; off; off >>= 1) v += __shfl_xor(v, off, 64);
  return v;
}

// ---------- Kernel 1: fused QKV projection (full-K per wave tile) -----------
// grid 384: 16-col tiles over N=3*2048. Wave w owns m-tile w, full K=2048.
__global__ __launch_bounds__(256) void k_qkvp(
    const float* __restrict__ hs, const float* __restrict__ Wq,
    const float* __restrict__ Wk, const float* __restrict__ Wv,
    const float* __restrict__ bq, const float* __restrict__ bk,
    const float* __restrict__ bv, unsigned short* __restrict__ qws,
    float* __restrict__ knew, float* __restrict__ vnew) {
  const int n0 = blockIdx.x * 16;
  const int p = n0 >> 11;                 // 0:q 1:k 2:v
  const int c0 = n0 & 2047;
  const float* W = (p == 0) ? Wq : (p == 1) ? Wk : Wv;
  const float* bias = (p == 0) ? bq : (p == 1) ? bk : bv;
  const int t = threadIdx.x, lane = t & 63, w = t >> 6;
  const int cl = lane & 15, q = lane >> 4;

  const float* arow = hs + (size_t)(w * 16 + cl) * 2048 + q * 8;   // A row
  const float* brow = W + (size_t)(c0 + cl) * 2048 + q * 8;        // W row

  f4 acc = fzero();
  #pragma unroll 8
  for (int k0 = 0; k0 < 2048; k0 += 32) {
    f4 a0 = *reinterpret_cast<const f4*>(arow + k0);
    f4 a1 = *reinterpret_cast<const f4*>(arow + k0 + 4);
    f4 b0 = *reinterpret_cast<const f4*>(brow + k0);
    f4 b1 = *reinterpret_cast<const f4*>(brow + k0 + 4);
    acc = mfma16(cvt8(a0, a1), cvt8(b0, b1), acc);
  }
  const int c = c0 + cl, h = c >> 6, d = c & 63;
  #pragma unroll
  for (int rg = 0; rg < 4; ++rg) {
    const int r = w * 16 + q * 4 + rg;    // global row (b*4+t)
    const int b = r >> 2, tt = r & 3;
    float v = acc[rg] + bias[c];
    if (p == 0) {
      qws[h * 4608 + r * 72 + d] = f2bs(v * 0.125f);
    } else if (p == 1) {
      knew[((h * 16 + b) * 4 + tt) * 64 + d] = v;
    } else {
      vnew[((h * 16 + b) * 4 + tt) * 64 + d] = v;
    }
  }
}

// --------- Kernel 2: flash partial attention over past KV chunks -------------
// grid 512: h = bx&31, chunk = bx>>5 (256 past positions). Scores in regs.
__global__ __launch_bounds__(256) void k_flash(
    const unsigned short* __restrict__ qws, const float* __restrict__ Kp,
    const float* __restrict__ Vp, const float* __restrict__ mask,
    float* __restrict__ Opart, float* __restrict__ mpart,
    float* __restrict__ lpart) {
  __shared__ __align__(16) unsigned short Pb[64 * 264];   // P bf16; early: f32 scratch
  __shared__ __align__(16) unsigned short Vb[256 * 74];   // V bf16, pad->2-way banks
  __shared__ float mrow[64];
  __shared__ float psum[4][64];
  float* tmp = reinterpret_cast<float*>(Pb);              // [64][68] f32
  float* s2  = reinterpret_cast<float*>(Pb) + 64 * 68;    // [64][4]  f32

  const int bx = blockIdx.x;
  const int h = bx & 31, cch = bx >> 5;
  const int s0 = cch * 256;
  const int t = threadIdx.x, lane = t & 63, w = t >> 6;
  const int cl = lane & 15, q = lane >> 4;
  const float* Kh = Kp + (size_t)h * 4096 * 64;
  const float* Vh = Vp + (size_t)h * 4096 * 64;

  // stage V chunk -> bf16 LDS [256][74] (coalesced f4 reads, u32-pair writes)
  unsigned int* Vb32 = reinterpret_cast<unsigned int*>(Vb);
  #pragma unroll
  for (int i = 0; i < 16; ++i) {
    int idx = t + i * 256;                 // 0..4095 float4s
    int s = idx >> 4, d4 = (idx & 15) << 2;
    f4 v = *reinterpret_cast<const f4*>(Vh + (size_t)(s0 + s) * 64 + d4);
    unsigned int lo = (unsigned int)f2bs(v[0]) | ((unsigned int)f2bs(v[1]) << 16);
    unsigned int hi = (unsigned int)f2bs(v[2]) | ((unsigned int)f2bs(v[3]) << 16);
    int u = s * 37 + (d4 >> 1);
    Vb32[u] = lo; Vb32[u + 1] = hi;
  }

  // Q fragments straight from global (qws [H][64][72] bf16, 16B aligned)
  s8v afr[4][2];
  #pragma unroll
  for (int mt = 0; mt < 4; ++mt)
    #pragma unroll
    for (int k2 = 0; k2 < 2; ++k2)
      afr[mt][k2] = *reinterpret_cast<const s8v*>(
          qws + h * 4608 + (mt * 16 + cl) * 72 + k2 * 32 + q * 8);

  // QK^T into registers: wave w covers s-subtiles nt = 4w..4w+3
  f4 sc[4][4];
  #pragma unroll
  for (int ni = 0; ni < 4; ++ni)
    #pragma unroll
    for (int mt = 0; mt < 4; ++mt) sc[ni][mt] = fzero();
  #pragma unroll
  for (int ni = 0; ni < 4; ++ni) {
    const int srow = s0 + (w * 4 + ni) * 16 + cl;
    const float* kr = Kh + (size_t)srow * 64 + q * 8;
    #pragma unroll
    for (int k2 = 0; k2 < 2; ++k2) {
      f4 k0v = *reinterpret_cast<const f4*>(kr + k2 * 32);
      f4 k1v = *reinterpret_cast<const f4*>(kr + k2 * 32 + 4);
      s8v bf = cvt8(k0v, k1v);
      #pragma unroll
      for (int mt = 0; mt < 4; ++mt)
        sc[ni][mt] = mfma16(afr[mt][k2], bf, sc[ni][mt]);
    }
  }
  // + mask, clamp; per-(row) in-lane max over ni -> scratch
  #pragma unroll
  for (int mt = 0; mt < 4; ++mt)
    #pragma unroll
    for (int rg = 0; rg < 4; ++rg) {
      const int r = mt * 16 + q * 4 + rg;
      float mx = NEG_HUGE;
      #pragma unroll
      for (int ni = 0; ni < 4; ++ni) {
        const int col = s0 + (w * 4 + ni) * 16 + cl;
        float v = sc[ni][mt][rg] + mask[(size_t)r * 4100 + col];
        v = fmaxf(v, NEG_HUGE);
        sc[ni][mt][rg] = v;
        mx = fmaxf(mx, v);
      }
      tmp[r * 68 + w * 16 + cl] = mx;
    }
  __syncthreads();  // b1: Vb + tmp ready
  {  // quarter-reduce rows: thread (row = t>>2, qt = t&3)
    const int row = t >> 2, qt = t & 3;
    const float* tr = tmp + row * 68 + qt * 16;
    float m = fmaxf(fmaxf(tr[0], tr[1]), fmaxf(tr[2], tr[3]));
    #pragma unroll
    for (int j = 4; j < 16; j += 4)
      m = fmaxf(m, fmaxf(fmaxf(tr[j], tr[j+1]), fmaxf(tr[j+2], tr[j+3])));
    s2[row * 4 + qt] = m;
  }
  __syncthreads();  // b2
  if (t < 64) {
    float m = fmaxf(fmaxf(s2[t*4], s2[t*4+1]), fmaxf(s2[t*4+2], s2[t*4+3]));
    mrow[t] = m;
    mpart[(h * 16 + cch) * 64 + t] = m;
  }
  __syncthreads();  // b3: mrow ready; tmp/s2 dead -> Pb reusable
  // exp + write P (bf16) to LDS
  #pragma unroll
  for (int mt = 0; mt < 4; ++mt)
    #pragma unroll
    for (int rg = 0; rg < 4; ++rg) {
      const int r = mt * 16 + q * 4 + rg;
      const float m = mrow[r];
      #pragma unroll
      for (int ni = 0; ni < 4; ++ni) {
        float e = __expf(sc[ni][mt][rg] - m);
        Pb[r * 264 + (w * 4 + ni) * 16 + cl] = f2bs(e);
      }
    }
  __syncthreads();  // b4: P ready
  // row l-sums from P (consistent with bf16 P used in PV)
  {
    const int r = t & 63, qt = t >> 6;
    float s = 0.f;
    #pragma unroll
    for (int j8 = 0; j8 < 8; ++j8) {
      const unsigned short* pp = &Pb[r * 264 + qt * 64 + j8 * 8];
      #pragma unroll
      for (int j = 0; j < 8; ++j) s += bs2f(pp[j]);
    }
    psum[qt][r] = s;
  }
  // PV from LDS (P bf16 A-frags b128; V bf16 column reads, ~2-way banks)
  f4 oacc[4];
  #pragma unroll
  for (int mt = 0; mt < 4; ++mt) oacc[mt] = fzero();
  const int dcol = w * 16 + cl;
  #pragma unroll
  for (int k2 = 0; k2 < 8; ++k2) {
    const int sb = k2 * 32 + q * 8;
    s8v bf;
    #pragma unroll
    for (int j = 0; j < 8; ++j) bf[j] = (short)Vb[(sb + j) * 74 + dcol];
    #pragma unroll
    for (int mt = 0; mt < 4; ++mt) {
      s8v pa = *reinterpret_cast<const s8v*>(&Pb[(mt * 16 + cl) * 264 + sb]);
      oacc[mt] = mfma16(pa, bf, oacc[mt]);
    }
  }
  __syncthreads();  // b5: psum complete
  if (t < 64)
    lpart[(h * 16 + cch) * 64 + t] = psum[0][t] + psum[1][t] + psum[2][t] + psum[3][t];
  float* ob = Opart + (size_t)(h * 16 + cch) * 64 * 64;
  #pragma unroll
  for (int mt = 0; mt < 4; ++mt)
    #pragma unroll
    for (int rg = 0; rg < 4; ++rg)
      ob[(mt * 16 + q * 4 + rg) * 64 + dcol] = oacc[mt][rg];
}

// ------- Kernel 3: merge chunk partials + 4 new-token scores per (b,h) -------
// grid 512 x 256 threads: d = t&63, token tt = t>>6 (one wave per token)
__global__ __launch_bounds__(256) void k_merge(
    const unsigned short* __restrict__ qws, const float* __restrict__ knew,
    const float* __restrict__ vnew, const float* __restrict__ mask,
    const float* __restrict__ Opart, const float* __restrict__ mpart,
    const float* __restrict__ lpart, unsigned short* __restrict__ attn) {
  const int bx = blockIdx.x;
  const int h = bx & 31, b = bx >> 5;
  const int d = threadIdx.x & 63, tt = threadIdx.x >> 6;
  const int r = b * 4 + tt;
  float qd = bs2f(qws[h * 4608 + r * 72 + d]);
  float scn[4];
  #pragma unroll
  for (int tp = 0; tp < 4; ++tp) {
    float kn = knew[((h * 16 + b) * 4 + tp) * 64 + d];
    float s = wave_sum(qd * kn);
    s += mask[(size_t)r * 4100 + 4096 + tp];
    scn[tp] = fmaxf(s, NEG_HUGE);
  }
  float mi[16], li[16];
  float mtot = NEG_HUGE;
  #pragma unroll
  for (int i = 0; i < 16; ++i) {
    mi[i] = mpart[(h * 16 + i) * 64 + r];
    li[i] = lpart[(h * 16 + i) * 64 + r];
    mtot = fmaxf(mtot, mi[i]);
  }
  #pragma unroll
  for (int tp = 0; tp < 4; ++tp) mtot = fmaxf(mtot, scn[tp]);
  float ltot = 0.f, od = 0.f;
  #pragma unroll
  for (int i = 0; i < 16; ++i) {
    float fct = __expf(mi[i] - mtot);
    ltot += li[i] * fct;
    od += Opart[((size_t)(h * 16 + i) * 64 + r) * 64 + d] * fct;
  }
  #pragma unroll
  for (int tp = 0; tp < 4; ++tp) {
    float e = __expf(scn[tp] - mtot);
    ltot += e;
    od += e * vnew[((h * 16 + b) * 4 + tp) * 64 + d];
  }
  attn[(size_t)r * 2048 + h * 64 + d] = f2bs(od / ltot);
}

// ------ Kernel 4: output projection, in-block K-split, direct f32 out --------
// grid 128 x 512 threads: wave w: m-tile = w&3, K-half = w>>2
__global__ __launch_bounds__(512) void k_out(
    const unsigned short* __restrict__ attn, const float* __restrict__ Wo,
    const float* __restrict__ bo, float* __restrict__ out) {
  __shared__ float red[4][16][17];
  const int n0 = blockIdx.x * 16;
  const int t = threadIdx.x, lane = t & 63, w = t >> 6;
  const int mt = w & 3, kh = w >> 2;
  const int cl = lane & 15, q = lane >> 4;
  const unsigned short* arow = attn + (size_t)(mt * 16 + cl) * 2048;
  const float* brow = Wo + (size_t)(n0 + cl) * 2048;
  f4 acc = fzero();
  const int kb = kh * 1024 + q * 8;
  #pragma unroll 8
  for (int step = 0; step < 32; ++step) {
    const int k = kb + step * 32;
    s8v af = *reinterpret_cast<const s8v*>(arow + k);
    f4 b0 = *reinterpret_cast<const f4*>(brow + k);
    f4 b1 = *reinterpret_cast<const f4*>(brow + k + 4);
    acc = mfma16(af, cvt8(b0, b1), acc);
  }
  if (kh == 1) {
    #pragma unroll
    for (int rg = 0; rg < 4; ++rg) red[mt][q * 4 + rg][cl] = acc[rg];
  }
  __syncthreads();
  if (kh == 0) {
    const int c = n0 + cl;
    #pragma unroll
    for (int rg = 0; rg < 4; ++rg) {
      const int r = mt * 16 + q * 4 + rg;
      out[(size_t)r * 2048 + c] = acc[rg] + red[mt][q * 4 + rg][cl] + bo[c];
    }
  }
}

extern "C" void kernel_launch(void* const* d_in, const int* in_sizes, int n_in,
                              void* d_out, int out_size, void* d_ws, size_t ws_size,
                              hipStream_t stream) {
  const float* hs   = (const float*)d_in[0];
  const float* pk   = (const float*)d_in[1];
  const float* pv   = (const float*)d_in[2];
  const float* mask = (const float*)d_in[3];
  const float* Wq   = (const float*)d_in[4];
  const float* bq   = (const float*)d_in[5];
  const float* Wk   = (const float*)d_in[6];
  const float* bk   = (const float*)d_in[7];
  const float* Wv   = (const float*)d_in[8];
  const float* bv   = (const float*)d_in[9];
  const float* Wo   = (const float*)d_in[10];
  const float* bo   = (const float*)d_in[11];

  float* f = (float*)d_ws;                  // ~9.5 MB used
  float* Opart = f;                         // [32][16][64][64]
  float* mpart = Opart + 2097152;           // [32][16][64]
  float* lpart = mpart + 32768;
  float* knew  = lpart + 32768;             // [32][16][4][64]
  float* vnew  = knew + 131072;
  unsigned short* qws  = (unsigned short*)(vnew + 131072);  // [32][64][72] bf16
  unsigned short* attn = qws + 147456;                      // [64][2048] bf16

  k_qkvp<<<384, 256, 0, stream>>>(hs, Wq, Wk, Wv, bq, bk, bv, qws, knew, vnew);
  k_flash<<<512, 256, 0, stream>>>(qws, pk, pv, mask, Opart, mpart, lpart);
  k_merge<<<512, 256, 0, stream>>>(qws, knew, vnew, mask, Opart, mpart, lpart, attn);
  k_out<<<128, 512, 0, stream>>>(attn, Wo, bo, (float*)d_out);
}

// Round 4
// 219.324 us; speedup vs baseline: 1.1388x; 1.1388x over previous
//
#include <hip/hip_runtime.h>

// OPT attention: B=16 T=4 E=2048 H=32 HD=64 P=4096 S=4100, M=B*T=64 rows.
// R4: latency-bound fix — in-block K-split everywhere (24 waves/CU in GEMMs),
// 128-pos flash chunks (1024 blocks), hs pre-converted to bf16.
// MFMA mfma_f32_16x16x32_bf16: A[m=lane&15][k=quad*8+j], B[n=lane&15][k=quad*8+j],
// D col=lane&15, row=quad*4+reg (verified layouts). Output dtype: f32.

typedef float f4 __attribute__((ext_vector_type(4)));
typedef short s8v __attribute__((ext_vector_type(8)));

#define NEG_HUGE (-3.402823466e38f)

__device__ inline unsigned short f2bs(float x) {  // f32 -> bf16 bits (RNE)
  union { float f; unsigned int u; } a; a.f = x;
  unsigned int u = a.u;
  u += 0x7fffu + ((u >> 16) & 1u);
  return (unsigned short)(u >> 16);
}
__device__ inline float bs2f(unsigned short s) {
  union { unsigned int u; float f; } a; a.u = ((unsigned int)s) << 16;
  return a.f;
}
__device__ inline s8v cvt8(f4 a, f4 b) {
  s8v r;
  r[0]=(short)f2bs(a[0]); r[1]=(short)f2bs(a[1]); r[2]=(short)f2bs(a[2]); r[3]=(short)f2bs(a[3]);
  r[4]=(short)f2bs(b[0]); r[5]=(short)f2bs(b[1]); r[6]=(short)f2bs(b[2]); r[7]=(short)f2bs(b[3]);
  return r;
}
__device__ inline f4 mfma16(s8v a, s8v b, f4 c) {
  return __builtin_amdgcn_mfma_f32_16x16x32_bf16(a, b, c, 0, 0, 0);
}
__device__ inline f4 fzero() { f4 z = {0.f,0.f,0.f,0.f}; return z; }
__device__ inline float wave_sum(float v) {
  #pragma unroll
  for (int off = 32; off; off >>= 1) v += __shfl_xor(v, off, 64);
  return v;
}

// ---------------- Kernel 0: hs f32 -> bf16 [64][2048] ------------------------
__global__ __launch_bounds__(256) void k_hs2bf(
    const float* __restrict__ hs, unsigned short* __restrict__ hsb) {
  const int i = (blockIdx.x * 256 + threadIdx.x) * 8;   // 16384 threads
  f4 a0 = *reinterpret_cast<const f4*>(hs + i);
  f4 a1 = *reinterpret_cast<const f4*>(hs + i + 4);
  s8v r = cvt8(a0, a1);
  *reinterpret_cast<s8v*>(hsb + i) = r;
}

// ---------- Kernel 1: QKV projection, in-block K-split-4 ---------------------
// grid 768: n-tile = bx>>1 (16 cols), m-half = bx&1. 8 waves: mt=w&1, kq=w>>1.
__global__ __launch_bounds__(512) void k_qkvp(
    const unsigned short* __restrict__ hsb, const float* __restrict__ Wq,
    const float* __restrict__ Wk, const float* __restrict__ Wv,
    const float* __restrict__ bq, const float* __restrict__ bk,
    const float* __restrict__ bv, unsigned short* __restrict__ qws,
    float* __restrict__ knew, float* __restrict__ vnew) {
  __shared__ float red[6][16][17];
  const int n0 = (blockIdx.x >> 1) * 16;
  const int mh = blockIdx.x & 1;
  const int p = n0 >> 11;                 // 0:q 1:k 2:v
  const int c0 = n0 & 2047;
  const float* W = (p == 0) ? Wq : (p == 1) ? Wk : Wv;
  const float* bias = (p == 0) ? bq : (p == 1) ? bk : bv;
  const int t = threadIdx.x, lane = t & 63, w = t >> 6;
  const int mt = w & 1, kq = w >> 1;
  const int cl = lane & 15, q = lane >> 4;
  const int rbase = mh * 32 + mt * 16;

  const unsigned short* arow = hsb + (rbase + cl) * 2048 + kq * 512 + q * 8;
  const float* brow = W + (size_t)(c0 + cl) * 2048 + kq * 512 + q * 8;

  f4 acc = fzero();
  #pragma unroll
  for (int k0 = 0; k0 < 512; k0 += 32) {
    s8v af = *reinterpret_cast<const s8v*>(arow + k0);
    f4 b0 = *reinterpret_cast<const f4*>(brow + k0);
    f4 b1 = *reinterpret_cast<const f4*>(brow + k0 + 4);
    acc = mfma16(af, cvt8(b0, b1), acc);
  }
  if (kq) {
    #pragma unroll
    for (int rg = 0; rg < 4; ++rg) red[(kq - 1) * 2 + mt][q * 4 + rg][cl] = acc[rg];
  }
  __syncthreads();
  if (kq == 0) {
    const int c = c0 + cl, h = c >> 6, d = c & 63;
    #pragma unroll
    for (int rg = 0; rg < 4; ++rg) {
      const int rr = q * 4 + rg;
      const int r = rbase + rr;           // global row (b*4+t)
      const int b = r >> 2, tt = r & 3;
      float v = acc[rg] + red[mt][rr][cl] + red[2 + mt][rr][cl]
              + red[4 + mt][rr][cl] + bias[c];
      if (p == 0) {
        qws[h * 4608 + r * 72 + d] = f2bs(v * 0.125f);
      } else if (p == 1) {
        knew[((h * 16 + b) * 4 + tt) * 64 + d] = v;
      } else {
        vnew[((h * 16 + b) * 4 + tt) * 64 + d] = v;
      }
    }
  }
}

// --------- Kernel 2: flash partial attention, 128-pos chunks -----------------
// grid 1024: h = bx&31, chunk = bx>>5 (128 past positions). Scores in regs.
__global__ __launch_bounds__(256) void k_flash(
    const unsigned short* __restrict__ qws, const float* __restrict__ Kp,
    const float* __restrict__ Vp, const float* __restrict__ mask,
    float* __restrict__ Opart, float* __restrict__ mpart,
    float* __restrict__ lpart) {
  __shared__ __align__(16) unsigned short Pb[64 * 136];   // P bf16; early: f32 tmp[64][68]
  __shared__ __align__(16) unsigned short Vb[128 * 74];   // V bf16, pad->2-way banks
  __shared__ float s2[256];
  __shared__ float mrow[64];
  __shared__ float psum[4][64];
  float* tmp = reinterpret_cast<float*>(Pb);              // [64][68] f32

  const int bx = blockIdx.x;
  const int h = bx & 31, cch = bx >> 5;                   // cch in [0,32)
  const int s0 = cch * 128;
  const int t = threadIdx.x, lane = t & 63, w = t >> 6;
  const int cl = lane & 15, q = lane >> 4;
  const float* Kh = Kp + (size_t)h * 4096 * 64;
  const float* Vh = Vp + (size_t)h * 4096 * 64;

  // stage V chunk -> bf16 LDS [128][74]
  unsigned int* Vb32 = reinterpret_cast<unsigned int*>(Vb);
  #pragma unroll
  for (int i = 0; i < 8; ++i) {
    int idx = t + i * 256;                 // 0..2047 float4s
    int s = idx >> 4, d4 = (idx & 15) << 2;
    f4 v = *reinterpret_cast<const f4*>(Vh + (size_t)(s0 + s) * 64 + d4);
    unsigned int lo = (unsigned int)f2bs(v[0]) | ((unsigned int)f2bs(v[1]) << 16);
    unsigned int hi = (unsigned int)f2bs(v[2]) | ((unsigned int)f2bs(v[3]) << 16);
    int u = s * 37 + (d4 >> 1);
    Vb32[u] = lo; Vb32[u + 1] = hi;
  }

  // Q fragments straight from global (qws [H][64][72] bf16, 16B aligned)
  s8v afr[4][2];
  #pragma unroll
  for (int mt = 0; mt < 4; ++mt)
    #pragma unroll
    for (int k2 = 0; k2 < 2; ++k2)
      afr[mt][k2] = *reinterpret_cast<const s8v*>(
          qws + h * 4608 + (mt * 16 + cl) * 72 + k2 * 32 + q * 8);

  // QK^T into registers: wave w covers s-subtiles nt = 2w, 2w+1
  f4 sc[2][4];
  #pragma unroll
  for (int ni = 0; ni < 2; ++ni)
    #pragma unroll
    for (int mt = 0; mt < 4; ++mt) sc[ni][mt] = fzero();
  #pragma unroll
  for (int ni = 0; ni < 2; ++ni) {
    const int srow = s0 + (w * 2 + ni) * 16 + cl;
    const float* kr = Kh + (size_t)srow * 64 + q * 8;
    #pragma unroll
    for (int k2 = 0; k2 < 2; ++k2) {
      f4 k0v = *reinterpret_cast<const f4*>(kr + k2 * 32);
      f4 k1v = *reinterpret_cast<const f4*>(kr + k2 * 32 + 4);
      s8v bf = cvt8(k0v, k1v);
      #pragma unroll
      for (int mt = 0; mt < 4; ++mt)
        sc[ni][mt] = mfma16(afr[mt][k2], bf, sc[ni][mt]);
    }
  }
  // + mask, clamp; per-row in-lane max -> tmp
  #pragma unroll
  for (int mt = 0; mt < 4; ++mt)
    #pragma unroll
    for (int rg = 0; rg < 4; ++rg) {
      const int r = mt * 16 + q * 4 + rg;
      float mx = NEG_HUGE;
      #pragma unroll
      for (int ni = 0; ni < 2; ++ni) {
        const int col = s0 + (w * 2 + ni) * 16 + cl;
        float v = sc[ni][mt][rg] + mask[(size_t)r * 4100 + col];
        v = fmaxf(v, NEG_HUGE);
        sc[ni][mt][rg] = v;
        mx = fmaxf(mx, v);
      }
      tmp[r * 68 + w * 16 + cl] = mx;
    }
  __syncthreads();  // b1: Vb + tmp ready
  {  // quarter-reduce rows: thread (row = t>>2, qt = t&3)
    const int row = t >> 2, qt = t & 3;
    const float* tr = tmp + row * 68 + qt * 16;
    float m = fmaxf(fmaxf(tr[0], tr[1]), fmaxf(tr[2], tr[3]));
    #pragma unroll
    for (int j = 4; j < 16; j += 4)
      m = fmaxf(m, fmaxf(fmaxf(tr[j], tr[j+1]), fmaxf(tr[j+2], tr[j+3])));
    s2[row * 4 + qt] = m;
  }
  __syncthreads();  // b2
  if (t < 64) {
    float m = fmaxf(fmaxf(s2[t*4], s2[t*4+1]), fmaxf(s2[t*4+2], s2[t*4+3]));
    mrow[t] = m;
    mpart[(h * 32 + cch) * 64 + t] = m;
  }
  __syncthreads();  // b3: mrow ready; tmp dead -> Pb reusable
  // exp + write P (bf16) to LDS
  #pragma unroll
  for (int mt = 0; mt < 4; ++mt)
    #pragma unroll
    for (int rg = 0; rg < 4; ++rg) {
      const int r = mt * 16 + q * 4 + rg;
      const float m = mrow[r];
      #pragma unroll
      for (int ni = 0; ni < 2; ++ni) {
        float e = __expf(sc[ni][mt][rg] - m);
        Pb[r * 136 + (w * 2 + ni) * 16 + cl] = f2bs(e);
      }
    }
  __syncthreads();  // b4: P ready
  // row l-sums from P (consistent with bf16 P used in PV)
  {
    const int r = t & 63, qt = t >> 6;
    float s = 0.f;
    #pragma unroll
    for (int j8 = 0; j8 < 4; ++j8) {
      const unsigned short* pp = &Pb[r * 136 + qt * 32 + j8 * 8];
      #pragma unroll
      for (int j = 0; j < 8; ++j) s += bs2f(pp[j]);
    }
    psum[qt][r] = s;
  }
  // PV from LDS
  f4 oacc[4];
  #pragma unroll
  for (int mt = 0; mt < 4; ++mt) oacc[mt] = fzero();
  const int dcol = w * 16 + cl;
  #pragma unroll
  for (int k2 = 0; k2 < 4; ++k2) {
    const int sb = k2 * 32 + q * 8;
    s8v bf;
    #pragma unroll
    for (int j = 0; j < 8; ++j) bf[j] = (short)Vb[(sb + j) * 74 + dcol];
    #pragma unroll
    for (int mt = 0; mt < 4; ++mt) {
      s8v pa = *reinterpret_cast<const s8v*>(&Pb[(mt * 16 + cl) * 136 + sb]);
      oacc[mt] = mfma16(pa, bf, oacc[mt]);
    }
  }
  __syncthreads();  // b5: psum complete
  if (t < 64)
    lpart[(h * 32 + cch) * 64 + t] = psum[0][t] + psum[1][t] + psum[2][t] + psum[3][t];
  float* ob = Opart + (size_t)(h * 32 + cch) * 64 * 64;
  #pragma unroll
  for (int mt = 0; mt < 4; ++mt)
    #pragma unroll
    for (int rg = 0; rg < 4; ++rg)
      ob[(mt * 16 + q * 4 + rg) * 64 + dcol] = oacc[mt][rg];
}

// ------- Kernel 3: merge 32 chunk partials + 4 new-token scores --------------
// grid 512 x 256 threads: d = t&63, token tt = t>>6 (one wave per token)
__global__ __launch_bounds__(256) void k_merge(
    const unsigned short* __restrict__ qws, const float* __restrict__ knew,
    const float* __restrict__ vnew, const float* __restrict__ mask,
    const float* __restrict__ Opart, const float* __restrict__ mpart,
    const float* __restrict__ lpart, unsigned short* __restrict__ attn) {
  const int bx = blockIdx.x;
  const int h = bx & 31, b = bx >> 5;
  const int d = threadIdx.x & 63, tt = threadIdx.x >> 6;
  const int r = b * 4 + tt;
  float qd = bs2f(qws[h * 4608 + r * 72 + d]);
  float scn[4];
  #pragma unroll
  for (int tp = 0; tp < 4; ++tp) {
    float kn = knew[((h * 16 + b) * 4 + tp) * 64 + d];
    float s = wave_sum(qd * kn);
    s += mask[(size_t)r * 4100 + 4096 + tp];
    scn[tp] = fmaxf(s, NEG_HUGE);
  }
  float mi[32], li[32];
  float mtot = NEG_HUGE;
  #pragma unroll
  for (int i = 0; i < 32; ++i) {
    mi[i] = mpart[(h * 32 + i) * 64 + r];
    li[i] = lpart[(h * 32 + i) * 64 + r];
    mtot = fmaxf(mtot, mi[i]);
  }
  #pragma unroll
  for (int tp = 0; tp < 4; ++tp) mtot = fmaxf(mtot, scn[tp]);
  float ltot = 0.f, od = 0.f;
  #pragma unroll
  for (int i = 0; i < 32; ++i) {
    float fct = __expf(mi[i] - mtot);
    ltot += li[i] * fct;
    od += Opart[((size_t)(h * 32 + i) * 64 + r) * 64 + d] * fct;
  }
  #pragma unroll
  for (int tp = 0; tp < 4; ++tp) {
    float e = __expf(scn[tp] - mtot);
    ltot += e;
    od += e * vnew[((h * 16 + b) * 4 + tp) * 64 + d];
  }
  attn[(size_t)r * 2048 + h * 64 + d] = f2bs(od / ltot);
}

// ------ Kernel 4: output projection, in-block K-split-4, f32 out -------------
// grid 256: n-tile = bx>>1 (16 cols), m-half = bx&1. 8 waves: mt=w&1, kq=w>>1.
__global__ __launch_bounds__(512) void k_out(
    const unsigned short* __restrict__ attn, const float* __restrict__ Wo,
    const float* __restrict__ bo, float* __restrict__ out) {
  __shared__ float red[6][16][17];
  const int n0 = (blockIdx.x >> 1) * 16;
  const int mh = blockIdx.x & 1;
  const int t = threadIdx.x, lane = t & 63, w = t >> 6;
  const int mt = w & 1, kq = w >> 1;
  const int cl = lane & 15, q = lane >> 4;
  const int rbase = mh * 32 + mt * 16;
  const unsigned short* arow = attn + (size_t)(rbase + cl) * 2048 + kq * 512 + q * 8;
  const float* brow = Wo + (size_t)(n0 + cl) * 2048 + kq * 512 + q * 8;
  f4 acc = fzero();
  #pragma unroll
  for (int k0 = 0; k0 < 512; k0 += 32) {
    s8v af = *reinterpret_cast<const s8v*>(arow + k0);
    f4 b0 = *reinterpret_cast<const f4*>(brow + k0);
    f4 b1 = *reinterpret_cast<const f4*>(brow + k0 + 4);
    acc = mfma16(af, cvt8(b0, b1), acc);
  }
  if (kq) {
    #pragma unroll
    for (int rg = 0; rg < 4; ++rg) red[(kq - 1) * 2 + mt][q * 4 + rg][cl] = acc[rg];
  }
  __syncthreads();
  if (kq == 0) {
    const int c = n0 + cl;
    #pragma unroll
    for (int rg = 0; rg < 4; ++rg) {
      const int rr = q * 4 + rg;
      out[(size_t)(rbase + rr) * 2048 + c] =
          acc[rg] + red[mt][rr][cl] + red[2 + mt][rr][cl] + red[4 + mt][rr][cl] + bo[c];
    }
  }
}

extern "C" void kernel_launch(void* const* d_in, const int* in_sizes, int n_in,
                              void* d_out, int out_size, void* d_ws, size_t ws_size,
                              hipStream_t stream) {
  const float* hs   = (const float*)d_in[0];
  const float* pk   = (const float*)d_in[1];
  const float* pv   = (const float*)d_in[2];
  const float* mask = (const float*)d_in[3];
  const float* Wq   = (const float*)d_in[4];
  const float* bq   = (const float*)d_in[5];
  const float* Wk   = (const float*)d_in[6];
  const float* bk   = (const float*)d_in[7];
  const float* Wv   = (const float*)d_in[8];
  const float* bv   = (const float*)d_in[9];
  const float* Wo   = (const float*)d_in[10];
  const float* bo   = (const float*)d_in[11];

  float* f = (float*)d_ws;                  // ~19.2 MB used
  float* Opart = f;                         // [32][32][64][64]
  float* mpart = Opart + 4194304;           // [32][32][64]
  float* lpart = mpart + 65536;
  float* knew  = lpart + 65536;             // [32][16][4][64]
  float* vnew  = knew + 131072;
  unsigned short* hsb  = (unsigned short*)(vnew + 131072);  // [64][2048] bf16
  unsigned short* qws  = hsb + 131072;                      // [32][64][72] bf16
  unsigned short* attn = qws + 147456;                      // [64][2048] bf16

  k_hs2bf<<<64, 256, 0, stream>>>(hs, hsb);
  k_qkvp<<<768, 512, 0, stream>>>(hsb, Wq, Wk, Wv, bq, bk, bv, qws, knew, vnew);
  k_flash<<<1024, 256, 0, stream>>>(qws, pk, pv, mask, Opart, mpart, lpart);
  k_merge<<<512, 256, 0, stream>>>(qws, knew, vnew, mask, Opart, mpart, lpart, attn);
  k_out<<<256, 512, 0, stream>>>(attn, Wo, bo, (float*)d_out);
}